// Round 3
// baseline (150.069 us; speedup 1.0000x reference)
//
#include <hip/hip_runtime.h>
#include <hip/hip_bf16.h>
#include <math.h>

#define NB 4096   // batch
#define ND 2048   // feature dim
#define BM 128
#define BK 32     // K per LDS tile (double-buffered)
#define NT (ND / BK)    // 64 K-tiles
#define NTB (NB / BM)   // 32 tile-blocks per dim
#define TPAD 136        // padded fp16 tile row

typedef __attribute__((ext_vector_type(8))) short short8;
typedef __attribute__((ext_vector_type(4))) float floatx4;
typedef __attribute__((ext_vector_type(4))) unsigned short ushort4v;

#define GLOAD_LDS16(g, l) \
  __builtin_amdgcn_global_load_lds((const __attribute__((address_space(1))) void*)(g), \
                                   (__attribute__((address_space(3))) void*)(l), 16, 0, 0)

// order-preserving float<->uint encode (min/max via unsigned atomics)
__device__ __forceinline__ unsigned fenc(float f) {
  unsigned u = __float_as_uint(f);
  return (u >> 31) ? ~u : (u | 0x80000000u);
}
__device__ __forceinline__ float fdec(unsigned u) {
  unsigned b = (u & 0x80000000u) ? (u ^ 0x80000000u) : ~u;
  return __uint_as_float(b);
}

__device__ __forceinline__ unsigned f2bf(float x) {  // RNE fp32 -> bf16 bits
  unsigned u = __float_as_uint(x);
  return (u + 0x7FFFu + ((u >> 16) & 1u)) >> 16;
}

union H16 { unsigned short u; _Float16 h; };
__device__ __forceinline__ unsigned short f2h(float x) { H16 c; c.h = (_Float16)x; return c.u; }
__device__ __forceinline__ float h2f(unsigned short u) { H16 c; c.u = u; return (float)c.h; }

// ---- kernel 1: L2-normalize rows, write bf16 matrix into ws ----
__global__ __launch_bounds__(256) void norm_kernel(const float* __restrict__ feats,
                                                   unsigned short* __restrict__ fb) {
  int row = blockIdx.x;
  int t = threadIdx.x;
  const float4* src = (const float4*)(feats + (size_t)row * ND);
  float4 v0 = src[t * 2];
  float4 v1 = src[t * 2 + 1];
  float ss = v0.x * v0.x + v0.y * v0.y + v0.z * v0.z + v0.w * v0.w +
             v1.x * v1.x + v1.y * v1.y + v1.z * v1.z + v1.w * v1.w;
  for (int off = 32; off > 0; off >>= 1) ss += __shfl_down(ss, off);
  __shared__ float wsum[4];
  int lane = t & 63, wid = t >> 6;
  if (lane == 0) wsum[wid] = ss;
  __syncthreads();
  float tot = wsum[0] + wsum[1] + wsum[2] + wsum[3];
  float inv = 1.0f / (sqrtf(tot) + 1e-12f);
  float a0 = v0.x * inv, a1 = v0.y * inv, a2 = v0.z * inv, a3 = v0.w * inv;
  float a4 = v1.x * inv, a5 = v1.y * inv, a6 = v1.z * inv, a7 = v1.w * inv;
  uint4 o;
  o.x = f2bf(a0) | (f2bf(a1) << 16);
  o.y = f2bf(a2) | (f2bf(a3) << 16);
  o.z = f2bf(a4) | (f2bf(a5) << 16);
  o.w = f2bf(a6) | (f2bf(a7) << 16);
  ((uint4*)(fb + (size_t)row * ND))[t] = o;
}

// ---- kernel 2: init row stats + zero sums ----
__global__ void init_kernel(unsigned* gpm, unsigned* gnm, float* gps, float* gns) {
  int i = blockIdx.x * blockDim.x + threadIdx.x;
  if (i < NB) {
    gpm[i] = 0xFFFFFFFFu;  // decodes to NaN -> comparisons false (empty-min semantics)
    gnm[i] = 0u;           // decodes to NaN
    gps[i] = 0.f;
    gns[i] = 0.f;
  }
}

// staging: per thread 2 A-chunks + 2 B-chunks of 16B, linear LDS dest (wave base + lane*16)
__device__ __forceinline__ void stage_tile(const unsigned short* __restrict__ fb,
                                           int row0, int col0, int kt,
                                           unsigned short* A, unsigned short* B,
                                           int w, int l) {
  int srow = w * 16 + (l >> 2);
  int scol = (l & 3) * 8;
#pragma unroll
  for (int i = 0; i < 2; i++) {
    GLOAD_LDS16(fb + (size_t)(row0 + i * 64 + srow) * ND + kt * BK + scol,
                (char*)A + (i * 64 + w * 16) * 64);
    GLOAD_LDS16(fb + (size_t)(col0 + i * 64 + srow) * ND + kt * BK + scol,
                (char*)B + (i * 64 + w * 16) * 64);
  }
}

// ---- kernel 3: symmetric GEMM over upper-tri blocks, 2-phase double-buffered ----
// Row+col min/max stats fused; stores fp16 tile (upper-triangle tiles only).
__global__ __launch_bounds__(256) void pass0_kernel(const unsigned short* __restrict__ fb,
                                                    const int* __restrict__ labels,
                                                    unsigned* __restrict__ gpm,
                                                    unsigned* __restrict__ gnm,
                                                    unsigned short* __restrict__ sim) {
  __shared__ __align__(16) char shraw[TPAD * BM * 2];  // 34816 B: GEMM bufs, then fp16 tile
  unsigned short* As0 = (unsigned short*)shraw;        // [128*32] = 8KB
  unsigned short* Bs0 = As0 + BM * BK;
  unsigned short* As1 = Bs0 + BM * BK;
  unsigned short* Bs1 = As1 + BM * BK;                 // total 32KB <= 34816
  __shared__ int rowlab[BM], collab[BM];
  __shared__ unsigned pmR[BM], nmR[BM], pmC[BM], nmC[BM];

  int t = threadIdx.x;
  int l = t & 63, w = t >> 6;
  int wr = w >> 1, wc = w & 1;

  // decode upper-triangular block index
  int rem = blockIdx.x, bi = 0;
  while (rem >= NTB - bi) { rem -= NTB - bi; bi++; }
  int bj = bi + rem;
  int row0 = bi * BM, col0 = bj * BM;

  if (t < BM) {
    rowlab[t] = labels[row0 + t];
    collab[t] = labels[col0 + t];
    pmR[t] = 0xFFFFFFFFu; nmR[t] = 0u;
    pmC[t] = 0xFFFFFFFFu; nmC[t] = 0u;
  }

  floatx4 acc[4][4];
#pragma unroll
  for (int m = 0; m < 4; m++)
#pragma unroll
    for (int n = 0; n < 4; n++) acc[m][n] = (floatx4){0.f, 0.f, 0.f, 0.f};

  stage_tile(fb, row0, col0, 0, As0, Bs0, w, l);
  __syncthreads();

#pragma unroll 2
  for (int kt = 0; kt < NT; kt++) {
    unsigned short* A  = (kt & 1) ? As1 : As0;
    unsigned short* B  = (kt & 1) ? Bs1 : Bs0;
    unsigned short* An = (kt & 1) ? As0 : As1;
    unsigned short* Bn = (kt & 1) ? Bs0 : Bs1;
    if (kt + 1 < NT) stage_tile(fb, row0, col0, kt + 1, An, Bn, w, l);
    short8 a[4], b[4];
#pragma unroll
    for (int m = 0; m < 4; m++)
      a[m] = *(const short8*)(A + (wr * 64 + m * 16 + (l & 15)) * BK + (l >> 4) * 8);
#pragma unroll
    for (int n = 0; n < 4; n++)
      b[n] = *(const short8*)(B + (wc * 64 + n * 16 + (l & 15)) * BK + (l >> 4) * 8);
#pragma unroll
    for (int m = 0; m < 4; m++)
#pragma unroll
      for (int n = 0; n < 4; n++)
        acc[m][n] = __builtin_amdgcn_mfma_f32_16x16x32_bf16(a[m], b[n], acc[m][n], 0, 0, 0);
    __syncthreads();  // everyone done reading A/B; next iter overwrites them
  }

  // ---- stats (C/D layout: col = lane&15, row = (lane>>4)*4 + reg) ----
#pragma unroll
  for (int m = 0; m < 4; m++) {
#pragma unroll
    for (int v = 0; v < 4; v++) {
      int row_l = wr * 64 + m * 16 + (l >> 4) * 4 + v;
      int rl = rowlab[row_l];
      int grow = row0 + row_l;
      float pmin = 3.0e38f, nmax = -3.0e38f;
      bool anyp = false, anyn = false;
#pragma unroll
      for (int n = 0; n < 4; n++) {
        int col_l = wc * 64 + n * 16 + (l & 15);
        float s = acc[m][n][v];
        if (rl == collab[col_l]) {
          if ((col0 + col_l) != grow && s < 0.99999f) { pmin = fminf(pmin, s); anyp = true; }
        } else {
          nmax = fmaxf(nmax, s);
          anyn = true;
        }
      }
      if (anyp) atomicMin(&pmR[row_l], fenc(pmin));
      if (anyn) atomicMax(&nmR[row_l], fenc(nmax));
    }
  }
  // col-attributed (mirror rows); idempotent on diagonal blocks
#pragma unroll
  for (int n = 0; n < 4; n++) {
    int col_l = wc * 64 + n * 16 + (l & 15);
    int cl = collab[col_l];
    int gcol = col0 + col_l;
    float pmin = 3.0e38f, nmax = -3.0e38f;
    bool anyp = false, anyn = false;
#pragma unroll
    for (int m = 0; m < 4; m++) {
#pragma unroll
      for (int v = 0; v < 4; v++) {
        int row_l = wr * 64 + m * 16 + (l >> 4) * 4 + v;
        float s = acc[m][n][v];
        if (rowlab[row_l] == cl) {
          if ((row0 + row_l) != gcol && s < 0.99999f) { pmin = fminf(pmin, s); anyp = true; }
        } else {
          nmax = fmaxf(nmax, s);
          anyn = true;
        }
      }
    }
    if (anyp) atomicMin(&pmC[col_l], fenc(pmin));
    if (anyn) atomicMax(&nmC[col_l], fenc(nmax));
  }

  // ---- pack fp16 tile into LDS (overwrites GEMM bufs; K-loop's last barrier guards) ----
  unsigned short (*tile)[TPAD] = (unsigned short(*)[TPAD])shraw;
#pragma unroll
  for (int m = 0; m < 4; m++)
#pragma unroll
    for (int v = 0; v < 4; v++) {
      int row_l = wr * 64 + m * 16 + (l >> 4) * 4 + v;
#pragma unroll
      for (int n = 0; n < 4; n++) {
        int col_l = wc * 64 + n * 16 + (l & 15);
        tile[row_l][col_l] = f2h(acc[m][n][v]);
      }
    }
  __syncthreads();

  // ---- coalesced store (upper tile only; no mirror) ----
  {
    int r = t >> 1, h = t & 1;
    const unsigned short* src = &tile[r][h * 64];
    unsigned short* dst = sim + (size_t)(row0 + r) * NB + col0 + h * 64;
#pragma unroll
    for (int k = 0; k < 8; k++)
      *(short8*)(dst + k * 8) = *(const short8*)(src + k * 8);
  }

  if (t < BM) {
    if (pmR[t] != 0xFFFFFFFFu) atomicMin(&gpm[row0 + t], pmR[t]);
    if (nmR[t] != 0u) atomicMax(&gnm[row0 + t], nmR[t]);
    if (pmC[t] != 0xFFFFFFFFu) atomicMin(&gpm[col0 + t], pmC[t]);
    if (nmC[t] != 0u) atomicMax(&gnm[col0 + t], nmC[t]);
  }
}

// ---- kernel 4: tile-based masked exp-sums (row + col attribution per upper tile) ----
__global__ __launch_bounds__(256) void sums2_kernel(const unsigned short* __restrict__ sim,
                                                    const int* __restrict__ labels,
                                                    const unsigned* __restrict__ gpm,
                                                    const unsigned* __restrict__ gnm,
                                                    float* __restrict__ gps,
                                                    float* __restrict__ gns) {
  __shared__ __align__(16) unsigned short tile[BM][TPAD];
  __shared__ int rlab[BM], clab[BM];
  __shared__ float fpsC[BM], fnsC[BM];

  int t = threadIdx.x, l = t & 63;

  int rem = blockIdx.x, bi = 0;
  while (rem >= NTB - bi) { rem -= NTB - bi; bi++; }
  int bj = bi + rem;
  int row0 = bi * BM, col0 = bj * BM;

  if (t < BM) {
    rlab[t] = labels[row0 + t];
    clab[t] = labels[col0 + t];
    fpsC[t] = 0.f;
    fnsC[t] = 0.f;
  }
  __syncthreads();

  // ---- row pass (coalesced global read), also fills LDS tile ----
  {
    int r = t >> 1, h = t & 1;
    int grow = row0 + r;
    int rl = rlab[r];
    float pm = fdec(gpm[grow]);   // pos_min (NaN if none)
    float nm = fdec(gnm[grow]);   // neg_max
    const unsigned short* src = sim + (size_t)grow * NB + col0 + h * 64;
    float ps = 0.f, ns = 0.f;
#pragma unroll
    for (int k = 0; k < 8; k++) {
      short8 sv = *(const short8*)(src + k * 8);
      *(short8*)(&tile[r][h * 64 + k * 8]) = sv;
#pragma unroll
      for (int e = 0; e < 8; e++) {
        int jl = h * 64 + k * 8 + e;
        float s = h2f((unsigned short)sv[e]);
        if (clab[jl] == rl) {
          if ((col0 + jl) != grow && s < 0.99999f && (s - 0.1f < nm))
            ps += __expf(-2.0f * (s - 0.5f));
        } else {
          if (s + 0.1f > pm) ns += __expf(40.0f * (s - 0.5f));
        }
      }
    }
    ps += __shfl_xor(ps, 1);
    ns += __shfl_xor(ns, 1);
    if ((l & 1) == 0) {
      if (ps != 0.f) atomicAdd(&gps[grow], ps);
      if (ns != 0.f) atomicAdd(&gns[grow], ns);
    }
  }

  // ---- col pass (off-diagonal only): transposed attribution from LDS ----
  if (bi != bj) {
    __syncthreads();  // tile fully written
    int cg = (t & 31) * 4;        // 4 consecutive cols per thread
    int rbase = (t >> 5) * 16;    // 8 row-chunks of 16
    int cl4[4];
    float cpm[4], cnm[4], psc[4], nsc[4];
#pragma unroll
    for (int q = 0; q < 4; q++) {
      int gc = col0 + cg + q;
      cl4[q] = clab[cg + q];
      cpm[q] = fdec(gpm[gc]);
      cnm[q] = fdec(gnm[gc]);
      psc[q] = 0.f; nsc[q] = 0.f;
    }
#pragma unroll
    for (int k = 0; k < 16; k++) {
      int rr = rbase + k;
      int rl2 = rlab[rr];
      ushort4v sv = *(const ushort4v*)(&tile[rr][cg]);
#pragma unroll
      for (int q = 0; q < 4; q++) {
        float s = h2f(sv[q]);
        if (rl2 == cl4[q]) {   // self impossible: bi != bj
          if (s < 0.99999f && (s - 0.1f < cnm[q])) psc[q] += __expf(-2.0f * (s - 0.5f));
        } else {
          if (s + 0.1f > cpm[q]) nsc[q] += __expf(40.0f * (s - 0.5f));
        }
      }
    }
#pragma unroll
    for (int q = 0; q < 4; q++) {
      if (psc[q] != 0.f) atomicAdd(&fpsC[cg + q], psc[q]);
      if (nsc[q] != 0.f) atomicAdd(&fnsC[cg + q], nsc[q]);
    }
    __syncthreads();
    if (t < BM) {
      if (fpsC[t] != 0.f) atomicAdd(&gps[col0 + t], fpsC[t]);
      if (fnsC[t] != 0.f) atomicAdd(&gns[col0 + t], fnsC[t]);
    }
  }
}

// ---- kernel 5: finalize scalar loss ----
__global__ __launch_bounds__(256) void finalize_kernel(const float* __restrict__ gps,
                                                       const float* __restrict__ gns,
                                                       float* __restrict__ out) {
  int t = threadIdx.x;
  float sum = 0.f;
  for (int i = t; i < NB; i += 256) {
    float ps = gps[i], ns = gns[i];
    if (ps > 0.f && ns > 0.f) sum += 0.5f * log1pf(ps) + 0.025f * log1pf(ns);
  }
  for (int off = 32; off > 0; off >>= 1) sum += __shfl_down(sum, off);
  __shared__ float wsum[4];
  int lane = t & 63, wid = t >> 6;
  if (lane == 0) wsum[wid] = sum;
  __syncthreads();
  if (t == 0) out[0] = (wsum[0] + wsum[1] + wsum[2] + wsum[3]) / (float)NB;
}

extern "C" void kernel_launch(void* const* d_in, const int* in_sizes, int n_in,
                              void* d_out, int out_size, void* d_ws, size_t ws_size,
                              hipStream_t stream) {
  const float* feats = (const float*)d_in[0];
  const int* labels = (const int*)d_in[1];

  char* ws = (char*)d_ws;
  unsigned short* fb = (unsigned short*)ws;                  // 16 MB bf16 normalized feats
  size_t off = (size_t)NB * ND * 2;
  unsigned short* sim = (unsigned short*)(ws + off);         // 32 MB fp16 sim (upper tiles used)
  off += (size_t)NB * NB * 2;
  unsigned* gpm = (unsigned*)(ws + off); off += NB * 4;
  unsigned* gnm = (unsigned*)(ws + off); off += NB * 4;
  float* gps = (float*)(ws + off); off += NB * 4;
  float* gns = (float*)(ws + off); off += NB * 4;

  norm_kernel<<<NB, 256, 0, stream>>>(feats, fb);
  init_kernel<<<NB / 256, 256, 0, stream>>>(gpm, gnm, gps, gns);
  int nblk = NTB * (NTB + 1) / 2;  // 528 upper-tri blocks
  pass0_kernel<<<nblk, 256, 0, stream>>>(fb, labels, gpm, gnm, sim);
  sums2_kernel<<<nblk, 256, 0, stream>>>(sim, labels, gpm, gnm, gps, gns);
  finalize_kernel<<<1, 256, 0, stream>>>(gps, gns, (float*)d_out);
}

// Round 5
// 135.782 us; speedup vs baseline: 1.1052x; 1.1052x over previous
//
#include <hip/hip_runtime.h>
#include <hip/hip_bf16.h>
#include <math.h>

#define NB 4096   // batch
#define ND 2048   // feature dim
#define BM 128
#define BK 32     // K per LDS tile
#define NT (ND / BK)    // 64 K-tiles
#define NTB (NB / BM)   // 32 tile-blocks per dim
#define NBLK (NTB * (NTB + 1) / 2)  // 528 upper-tri blocks
#define TPAD 136        // padded fp16 tile row (272 B = 17*16, keeps short8 alignment)

typedef __attribute__((ext_vector_type(8))) short short8;
typedef __attribute__((ext_vector_type(4))) float floatx4;
typedef __attribute__((ext_vector_type(4))) unsigned short ushort4v;

#define GLOAD_LDS16(g, l) \
  __builtin_amdgcn_global_load_lds((const __attribute__((address_space(1))) void*)(g), \
                                   (__attribute__((address_space(3))) void*)(l), 16, 0, 0)

// order-preserving float<->uint encode (min/max via unsigned atomics)
__device__ __forceinline__ unsigned fenc(float f) {
  unsigned u = __float_as_uint(f);
  return (u >> 31) ? ~u : (u | 0x80000000u);
}
__device__ __forceinline__ float fdec(unsigned u) {
  unsigned b = (u & 0x80000000u) ? (u ^ 0x80000000u) : ~u;
  return __uint_as_float(b);
}

__device__ __forceinline__ unsigned f2bf(float x) {  // RNE fp32 -> bf16 bits
  unsigned u = __float_as_uint(x);
  return (u + 0x7FFFu + ((u >> 16) & 1u)) >> 16;
}

union H16 { unsigned short u; _Float16 h; };
__device__ __forceinline__ unsigned short f2h(float x) { H16 c; c.h = (_Float16)x; return c.u; }
__device__ __forceinline__ float h2f(unsigned short u) { H16 c; c.u = u; return (float)c.h; }

// ---- kernel 1: L2-normalize rows -> bf16; init min/max sentinels ----
__global__ __launch_bounds__(256) void norm_kernel(const float* __restrict__ feats,
                                                   unsigned short* __restrict__ fb,
                                                   unsigned* __restrict__ gpm,
                                                   unsigned* __restrict__ gnm) {
  int row = blockIdx.x;
  int t = threadIdx.x;
  if (t == 0) {
    gpm[row] = 0xFFFFFFFFu;  // atomicMin identity; decodes NaN -> masks false
    gnm[row] = 0u;           // atomicMax identity
  }
  const float4* src = (const float4*)(feats + (size_t)row * ND);
  float4 v0 = src[t * 2];
  float4 v1 = src[t * 2 + 1];
  float ss = v0.x * v0.x + v0.y * v0.y + v0.z * v0.z + v0.w * v0.w +
             v1.x * v1.x + v1.y * v1.y + v1.z * v1.z + v1.w * v1.w;
  for (int off = 32; off > 0; off >>= 1) ss += __shfl_down(ss, off);
  __shared__ float wsum[4];
  int lane = t & 63, wid = t >> 6;
  if (lane == 0) wsum[wid] = ss;
  __syncthreads();
  float tot = wsum[0] + wsum[1] + wsum[2] + wsum[3];
  float inv = 1.0f / (sqrtf(tot) + 1e-12f);
  uint4 o;
  o.x = f2bf(v0.x * inv) | (f2bf(v0.y * inv) << 16);
  o.y = f2bf(v0.z * inv) | (f2bf(v0.w * inv) << 16);
  o.z = f2bf(v1.x * inv) | (f2bf(v1.y * inv) << 16);
  o.w = f2bf(v1.z * inv) | (f2bf(v1.w * inv) << 16);
  ((uint4*)(fb + (size_t)row * ND))[t] = o;
}

// ---- kernel 2: pipelined symmetric GEMM over upper-tri blocks ----
// 3-deep staging, counted vmcnt (never 0 mid-loop), XOR chunk swizzle.
// Row+col min/max stats via shfl + global atomics; stores tile + transposed mirror.
__global__ __launch_bounds__(256) void pass0_kernel(const unsigned short* __restrict__ fb,
                                                    const int* __restrict__ labels,
                                                    unsigned* __restrict__ gpm,
                                                    unsigned* __restrict__ gnm,
                                                    unsigned short* __restrict__ sim) {
  // 3-deep (A,B) staging: 3*2*128*32*2B = 48 KB; tile phase reuses this region.
  __shared__ __align__(16) unsigned short bufs[3][2][BM * BK];
  __shared__ int rowlab[BM], collab[BM];

  int tid = threadIdx.x;
  int l = tid & 63, w = tid >> 6;
  int wr = w >> 1, wc = w & 1;

  int rem = blockIdx.x, bi = 0;
  while (rem >= NTB - bi) { rem -= NTB - bi; bi++; }
  int bj = bi + rem;
  int row0 = bi * BM, col0 = bj * BM;

  if (tid < BM) {
    rowlab[tid] = labels[row0 + tid];
    collab[tid] = labels[col0 + tid];
  }

  // stage K-tile kt into buffer q: LDS dest linear (wave base + lane*16),
  // XOR chunk-swizzle on the GLOBAL source (both-sides involution, rule #21).
  auto stage = [&](int kt, int q) {
#pragma unroll
    for (int i = 0; i < 2; i++) {
      int rloc = i * 64 + w * 16 + (l >> 2);
      int cs = ((l & 3) ^ ((rloc >> 1) & 3)) * 8;  // swizzled 16B chunk (elements)
      GLOAD_LDS16(fb + (size_t)(row0 + rloc) * ND + kt * BK + cs,
                  (char*)(&bufs[q][0][0]) + (size_t)(i * 64 + w * 16) * 64);
      GLOAD_LDS16(fb + (size_t)(col0 + rloc) * ND + kt * BK + cs,
                  (char*)(&bufs[q][1][0]) + (size_t)(i * 64 + w * 16) * 64);
    }
  };

  floatx4 acc[4][4];
#pragma unroll
  for (int m = 0; m < 4; m++)
#pragma unroll
    for (int n = 0; n < 4; n++) acc[m][n] = (floatx4){0.f, 0.f, 0.f, 0.f};

  stage(0, 0);
  stage(1, 1);
  stage(2, 2);
  asm volatile("s_waitcnt lgkmcnt(0)" ::: "memory");  // rowlab/collab writes drained

  for (int kt = 0; kt < NT; kt++) {
    int cur = kt % 3;
    // counted vmcnt: wait only for stage(kt)'s 4 loads; newer stages stay in flight
    if (kt < NT - 2)       asm volatile("s_waitcnt vmcnt(8)" ::: "memory");
    else if (kt == NT - 2) asm volatile("s_waitcnt vmcnt(4)" ::: "memory");
    else                   asm volatile("s_waitcnt vmcnt(0)" ::: "memory");
    __builtin_amdgcn_s_barrier();   // all waves' stage(kt) landed

    short8 a[4], b[4];
#pragma unroll
    for (int m = 0; m < 4; m++) {
      int r = wr * 64 + m * 16 + (l & 15);
      int c = ((l >> 4) ^ ((r >> 1) & 3)) * 8;
      a[m] = *(const short8*)(&bufs[cur][0][r * BK + c]);
    }
#pragma unroll
    for (int n = 0; n < 4; n++) {
      int r = wc * 64 + n * 16 + (l & 15);
      int c = ((l >> 4) ^ ((r >> 1) & 3)) * 8;
      b[n] = *(const short8*)(&bufs[cur][1][r * BK + c]);
    }
    asm volatile("s_waitcnt lgkmcnt(0)" ::: "memory");  // my frags in regs
    __builtin_amdgcn_s_barrier();   // everyone done reading bufs[cur]

    if (kt + 3 < NT) stage(kt + 3, cur);  // overwrite freed buffer; loads fly over MFMA

    __builtin_amdgcn_s_setprio(1);
#pragma unroll
    for (int m = 0; m < 4; m++)
#pragma unroll
      for (int n = 0; n < 4; n++)
        acc[m][n] = __builtin_amdgcn_mfma_f32_16x16x32_bf16(a[m], b[n], acc[m][n], 0, 0, 0);
    __builtin_amdgcn_s_setprio(0);
  }

  // ---- stats (C/D layout: col = lane&15, row = (lane>>4)*4 + reg), shfl-reduced ----
#pragma unroll
  for (int m = 0; m < 4; m++) {
#pragma unroll
    for (int v = 0; v < 4; v++) {
      int row_l = wr * 64 + m * 16 + (l >> 4) * 4 + v;
      int grow = row0 + row_l;
      int rl = rowlab[row_l];
      float pmin = 3.0e38f, nmax = -3.0e38f;
#pragma unroll
      for (int n = 0; n < 4; n++) {
        int col_l = wc * 64 + n * 16 + (l & 15);
        float s = acc[m][n][v];
        if (rl == collab[col_l]) {
          if ((col0 + col_l) != grow && s < 0.99999f) pmin = fminf(pmin, s);
        } else {
          nmax = fmaxf(nmax, s);
        }
      }
#pragma unroll
      for (int off = 1; off < 16; off <<= 1) {
        pmin = fminf(pmin, __shfl_xor(pmin, off));
        nmax = fmaxf(nmax, __shfl_xor(nmax, off));
      }
      if ((l & 15) == 0) {
        atomicMin(&gpm[grow], fenc(pmin));  // sentinels encode huge -> harmless
        atomicMax(&gnm[grow], fenc(nmax));
      }
    }
  }
  // col-attributed (mirror rows); idempotent on diagonal blocks
#pragma unroll
  for (int n = 0; n < 4; n++) {
    int col_l = wc * 64 + n * 16 + (l & 15);
    int gcol = col0 + col_l;
    int cl = collab[col_l];
    float pmin = 3.0e38f, nmax = -3.0e38f;
#pragma unroll
    for (int m = 0; m < 4; m++) {
#pragma unroll
      for (int v = 0; v < 4; v++) {
        int row_l = wr * 64 + m * 16 + (l >> 4) * 4 + v;
        float s = acc[m][n][v];
        if (rowlab[row_l] == cl) {
          if ((row0 + row_l) != gcol && s < 0.99999f) pmin = fminf(pmin, s);
        } else {
          nmax = fmaxf(nmax, s);
        }
      }
    }
    pmin = fminf(pmin, __shfl_xor(pmin, 16));
    pmin = fminf(pmin, __shfl_xor(pmin, 32));
    nmax = fmaxf(nmax, __shfl_xor(nmax, 16));
    nmax = fmaxf(nmax, __shfl_xor(nmax, 32));
    if ((l >> 4) == 0) {
      atomicMin(&gpm[gcol], fenc(pmin));
      atomicMax(&gnm[gcol], fenc(nmax));
    }
  }

  // ---- direct tile: build row-major fp16 in LDS (reuses bufs; reads all done) ----
  unsigned short (*tile)[TPAD] = (unsigned short(*)[TPAD])(&bufs[0][0][0]);
#pragma unroll
  for (int m = 0; m < 4; m++)
#pragma unroll
    for (int v = 0; v < 4; v++) {
      int row_l = wr * 64 + m * 16 + (l >> 4) * 4 + v;
#pragma unroll
      for (int n = 0; n < 4; n++)
        tile[row_l][wc * 64 + n * 16 + (l & 15)] = f2h(acc[m][n][v]);
    }
  __syncthreads();
  {
    int r = tid >> 1, h = tid & 1;
    const unsigned short* src = &tile[r][h * 64];
    unsigned short* dst = sim + (size_t)(row0 + r) * NB + col0 + h * 64;
#pragma unroll
    for (int k = 0; k < 8; k++)
      *(short8*)(dst + k * 8) = *(const short8*)(src + k * 8);
  }

  // ---- mirror tile (off-diagonal only; diagonal tile is symmetric) ----
  if (bi != bj) {
    __syncthreads();  // direct-store reads done; safe to overwrite region
    // packed transposed build: acc's 4 v-values = 4 consecutive orig-rows
    // = 4 consecutive elements of transposed row col_l -> one ds_write_b64
#pragma unroll
    for (int m = 0; m < 4; m++) {
      int rowb = wr * 64 + m * 16 + (l >> 4) * 4;
#pragma unroll
      for (int n = 0; n < 4; n++) {
        int col_l = wc * 64 + n * 16 + (l & 15);
        ushort4v pk;
        pk[0] = f2h(acc[m][n][0]);
        pk[1] = f2h(acc[m][n][1]);
        pk[2] = f2h(acc[m][n][2]);
        pk[3] = f2h(acc[m][n][3]);
        *(ushort4v*)(&tile[col_l][rowb]) = pk;  // 8B-aligned (rowb % 4 == 0)
      }
    }
    __syncthreads();
    int mr = tid >> 1, h = tid & 1;
    const unsigned short* src = &tile[mr][h * 64];
    unsigned short* dst = sim + (size_t)(col0 + mr) * NB + row0 + h * 64;
#pragma unroll
    for (int k = 0; k < 8; k++)
      *(short8*)(dst + k * 8) = *(const short8*)(src + k * 8);
  }
}

// ---- kernel 3: streaming masked exp-sums, one wave per row (full sim) ----
__global__ __launch_bounds__(256) void sums_kernel(const unsigned short* __restrict__ sim,
                                                   const int* __restrict__ labels,
                                                   const unsigned* __restrict__ gpm,
                                                   const unsigned* __restrict__ gnm,
                                                   float* __restrict__ gps,
                                                   float* __restrict__ gns) {
  int t = threadIdx.x, l = t & 63, w = t >> 6;
  int r = blockIdx.x * 4 + w;
  int rl = labels[r];
  float pm = fdec(gpm[r]);  // pos_min (NaN if none -> masks false)
  float nm = fdec(gnm[r]);  // neg_max
  const unsigned short* row = sim + (size_t)r * NB;
  float ps = 0.f, ns = 0.f;
#pragma unroll
  for (int it = 0; it < 8; it++) {
    int j0 = it * 512 + l * 8;
    short8 sv = *(const short8*)(row + j0);
    int4 lb0 = *(const int4*)(labels + j0);
    int4 lb1 = *(const int4*)(labels + j0 + 4);
    int lb[8] = {lb0.x, lb0.y, lb0.z, lb0.w, lb1.x, lb1.y, lb1.z, lb1.w};
#pragma unroll
    for (int e = 0; e < 8; e++) {
      float s = h2f((unsigned short)sv[e]);
      int j = j0 + e;
      if (lb[e] == rl) {
        if (j != r && s < 0.99999f && (s - 0.1f < nm)) ps += __expf(-2.0f * (s - 0.5f));
      } else {
        if (s + 0.1f > pm) ns += __expf(40.0f * (s - 0.5f));
      }
    }
  }
  for (int off = 32; off > 0; off >>= 1) {
    ps += __shfl_down(ps, off);
    ns += __shfl_down(ns, off);
  }
  if (l == 0) { gps[r] = ps; gns[r] = ns; }
}

// ---- kernel 4: finalize scalar loss ----
__global__ __launch_bounds__(256) void finalize_kernel(const float* __restrict__ gps,
                                                       const float* __restrict__ gns,
                                                       float* __restrict__ out) {
  int t = threadIdx.x;
  float sum = 0.f;
  for (int i = t; i < NB; i += 256) {
    float ps = gps[i], ns = gns[i];
    if (ps > 0.f && ns > 0.f) sum += 0.5f * log1pf(ps) + 0.025f * log1pf(ns);
  }
  for (int off = 32; off > 0; off >>= 1) sum += __shfl_down(sum, off);
  __shared__ float wsum[4];
  int lane = t & 63, wid = t >> 6;
  if (lane == 0) wsum[wid] = sum;
  __syncthreads();
  if (t == 0) out[0] = (wsum[0] + wsum[1] + wsum[2] + wsum[3]) / (float)NB;
}

extern "C" void kernel_launch(void* const* d_in, const int* in_sizes, int n_in,
                              void* d_out, int out_size, void* d_ws, size_t ws_size,
                              hipStream_t stream) {
  const float* feats = (const float*)d_in[0];
  const int* labels = (const int*)d_in[1];

  char* ws = (char*)d_ws;
  unsigned short* fb = (unsigned short*)ws;                  // 16 MB bf16 normalized feats
  size_t off = (size_t)NB * ND * 2;
  unsigned short* sim = (unsigned short*)(ws + off);         // 32 MB fp16 sim (full)
  off += (size_t)NB * NB * 2;
  unsigned* gpm = (unsigned*)(ws + off); off += NB * 4;
  unsigned* gnm = (unsigned*)(ws + off); off += NB * 4;
  float* gps = (float*)(ws + off); off += NB * 4;
  float* gns = (float*)(ws + off); off += NB * 4;

  norm_kernel<<<NB, 256, 0, stream>>>(feats, fb, gpm, gnm);
  pass0_kernel<<<NBLK, 256, 0, stream>>>(fb, labels, gpm, gnm, sim);
  sums_kernel<<<NB / 4, 256, 0, stream>>>(sim, labels, gpm, gnm, gps, gns);
  finalize_kernel<<<1, 256, 0, stream>>>(gps, gns, (float*)d_out);
}

// Round 6
// 120.457 us; speedup vs baseline: 1.2458x; 1.1272x over previous
//
#include <hip/hip_runtime.h>
#include <hip/hip_bf16.h>
#include <math.h>

#define NB 4096   // batch
#define ND 2048   // feature dim
#define BT 256    // output tile (256x256)
#define NTB (NB / BT)     // 16 tile-blocks per dim
#define NKT (ND / 64)     // 32 K-tiles of 64
#define NITER (NKT / 2)   // 16 iterations (2 K-tiles each)
#define TP 136            // transposed-pack padded row (ushorts)

typedef __attribute__((ext_vector_type(8))) short short8;
typedef __attribute__((ext_vector_type(4))) float floatx4;
typedef __attribute__((ext_vector_type(4))) unsigned short ushort4v;

#define GLOAD_LDS16(g, l) \
  __builtin_amdgcn_global_load_lds((const __attribute__((address_space(1))) void*)(g), \
                                   (__attribute__((address_space(3))) void*)(l), 16, 0, 0)

// order-preserving float<->uint encode (min/max via unsigned atomics)
__device__ __forceinline__ unsigned fenc(float f) {
  unsigned u = __float_as_uint(f);
  return (u >> 31) ? ~u : (u | 0x80000000u);
}
__device__ __forceinline__ float fdec(unsigned u) {
  unsigned b = (u & 0x80000000u) ? (u ^ 0x80000000u) : ~u;
  return __uint_as_float(b);
}

__device__ __forceinline__ unsigned f2bf(float x) {  // RNE fp32 -> bf16 bits
  unsigned u = __float_as_uint(x);
  return (u + 0x7FFFu + ((u >> 16) & 1u)) >> 16;
}

union H16 { unsigned short u; _Float16 h; };
__device__ __forceinline__ unsigned short f2h(float x) { H16 c; c.h = (_Float16)x; return c.u; }
__device__ __forceinline__ float h2f(unsigned short u) { H16 c; c.u = u; return (float)c.h; }

// ---- kernel 1: L2-normalize rows -> bf16; init min/max sentinels ----
__global__ __launch_bounds__(256) void norm_kernel(const float* __restrict__ feats,
                                                   unsigned short* __restrict__ fb,
                                                   unsigned* __restrict__ gpm,
                                                   unsigned* __restrict__ gnm) {
  int row = blockIdx.x;
  int t = threadIdx.x;
  if (t == 0) {
    gpm[row] = 0xFFFFFFFFu;  // decodes NaN -> masks false (empty-min semantics)
    gnm[row] = 0u;
  }
  const float4* src = (const float4*)(feats + (size_t)row * ND);
  float4 v0 = src[t * 2];
  float4 v1 = src[t * 2 + 1];
  float ss = v0.x * v0.x + v0.y * v0.y + v0.z * v0.z + v0.w * v0.w +
             v1.x * v1.x + v1.y * v1.y + v1.z * v1.z + v1.w * v1.w;
  for (int off = 32; off > 0; off >>= 1) ss += __shfl_down(ss, off);
  __shared__ float wsum[4];
  int lane = t & 63, wid = t >> 6;
  if (lane == 0) wsum[wid] = ss;
  __syncthreads();
  float tot = wsum[0] + wsum[1] + wsum[2] + wsum[3];
  float inv = 1.0f / (sqrtf(tot) + 1e-12f);
  uint4 o;
  o.x = f2bf(v0.x * inv) | (f2bf(v0.y * inv) << 16);
  o.y = f2bf(v0.z * inv) | (f2bf(v0.w * inv) << 16);
  o.z = f2bf(v1.x * inv) | (f2bf(v1.y * inv) << 16);
  o.w = f2bf(v1.z * inv) | (f2bf(v1.w * inv) << 16);
  ((uint4*)(fb + (size_t)row * ND))[t] = o;
}

// ---- kernel 2: 256x256-tile 8-wave 8-phase GEMM, full grid ----
// Stats (row-attributed) fused; stores TRANSPOSED fp16 tile (sim symmetric,
// each entry written exactly once).
__global__ __launch_bounds__(512, 2) void pass0_kernel(const unsigned short* __restrict__ fb,
                                                       const int* __restrict__ labels,
                                                       unsigned* __restrict__ gpm,
                                                       unsigned* __restrict__ gnm,
                                                       unsigned short* __restrict__ sim) {
  // 8 half-buffers of 16KB: index (o<<2)|(d<<1)|h ; o:0=A,1=B  d:dbuf  h:row-half
  __shared__ __align__(16) char shraw[131072];
  __shared__ int rowlab[BT], collab[BT];

  int tid = threadIdx.x;
  int l = tid & 63, wv = tid >> 6;
  int wm = wv >> 2, wn = wv & 3;   // 2 x 4 wave grid

  // XCD-clustered block mapping: each XCD owns 2 consecutive bi rows
  int bid = blockIdx.x;
  int bi = (bid & 7) * 2 + ((bid >> 3) >> 4);
  int bj = (bid >> 3) & 15;
  int row0 = bi * BT, col0 = bj * BT;

  if (tid < BT) {
    rowlab[tid] = labels[row0 + tid];
    collab[tid] = labels[col0 + tid];
  }

  auto lds_half = [&](int o, int d, int h) -> char* {
    return shraw + (size_t)(((o << 2) | (d << 1) | h) << 14);
  };
  // stage one 128x64 half-tile: linear LDS dest, XOR-swizzled global source
  auto stage = [&](int o, int d, int h, int t) {
#pragma unroll
    for (int e = 0; e < 2; e++) {
      int li = (wv * 2 + e) * 64 + l;
      int r = li >> 3, c = li & 7;
      GLOAD_LDS16(fb + (size_t)(((o ? col0 : row0) + h * 128) + r) * ND + t * 64 + ((c ^ (r & 7)) * 8),
                  lds_half(o, d, h) + (size_t)(wv * 2 + e) * 1024);
    }
  };

  floatx4 acc[8][4];
#pragma unroll
  for (int j = 0; j < 8; j++)
#pragma unroll
    for (int r = 0; r < 4; r++) acc[j][r] = (floatx4){0.f, 0.f, 0.f, 0.f};

  // per-lane LDS byte offsets (same for every phase; half ptr selects h)
  int offA[4][2], offB[2][2];
#pragma unroll
  for (int jl = 0; jl < 4; jl++) {
    int rh = (2 * jl + wm) * 16 + (l & 15);
#pragma unroll
    for (int ks = 0; ks < 2; ks++) {
      int ck = ks * 4 + (l >> 4);
      offA[jl][ks] = rh * 128 + ((ck ^ (rh & 7)) * 16);
    }
  }
#pragma unroll
  for (int rr = 0; rr < 2; rr++) {
    int rh = (wn + 4 * rr) * 16 + (l & 15);
#pragma unroll
    for (int ks = 0; ks < 2; ks++) {
      int ck = ks * 4 + (l >> 4);
      offB[rr][ks] = rh * 128 + ((ck ^ (rh & 7)) * 16);
    }
  }

  // prologue: tile0 (d0) fully, tile1 (d1) Bh0+Ah0; Ah1/Bh1 of tile1 staged in P1/P2
  stage(1, 0, 0, 0); stage(0, 0, 0, 0); stage(0, 0, 1, 0); stage(1, 0, 1, 0);
  stage(1, 1, 0, 1); stage(0, 1, 0, 1);
  asm volatile("s_waitcnt vmcnt(8)" ::: "memory");
  __builtin_amdgcn_s_barrier();

  for (int it = 0; it < NITER; it++) {
    bool lastIt = (it == NITER - 1);
#pragma unroll
    for (int dd = 0; dd < 2; dd++) {
      int t = 2 * it + dd;
      const char* A0 = lds_half(0, dd, 0);
      const char* A1 = lds_half(0, dd, 1);
      const char* B0 = lds_half(1, dd, 0);
      const char* B1 = lds_half(1, dd, 1);
      short8 b_[2][2];
#pragma unroll
      for (int q = 0; q < 4; q++) {
        // ---- ds-read subtile for this phase ----
        const char* Ah = (q & 1) ? A1 : A0;
        short8 a_[4][2];
#pragma unroll
        for (int jl = 0; jl < 4; jl++) {
          a_[jl][0] = *(const short8*)(Ah + offA[jl][0]);
          a_[jl][1] = *(const short8*)(Ah + offA[jl][1]);
        }
        if (q == 0 || q == 2) {
          const char* Bh = (q < 2) ? B0 : B1;
#pragma unroll
          for (int rr = 0; rr < 2; rr++) {
            b_[rr][0] = *(const short8*)(Bh + offB[rr][0]);
            b_[rr][1] = *(const short8*)(Bh + offB[rr][1]);
          }
        }
        // ---- stage one half-tile (pipelined ~5 phases ahead) ----
        if (q == 0) { if (t + 1 < NKT) stage(0, 1 - dd, 1, t + 1); }
        else if (q == 1) { if (t + 1 < NKT) stage(1, 1 - dd, 1, t + 1); }
        else if (q == 2) { if (t + 2 < NKT) stage(1, dd, 0, t + 2); }
        else             { if (t + 2 < NKT) stage(0, dd, 0, t + 2); }

        __builtin_amdgcn_s_barrier();
        asm volatile("s_waitcnt lgkmcnt(0)" ::: "memory");
        __builtin_amdgcn_sched_barrier(0);

        __builtin_amdgcn_s_setprio(1);
#pragma unroll
        for (int jl = 0; jl < 4; jl++)
#pragma unroll
          for (int rr = 0; rr < 2; rr++) {
            int ja = (q & 1) * 4 + jl, ra = (q >> 1) * 2 + rr;
            acc[ja][ra] = __builtin_amdgcn_mfma_f32_16x16x32_bf16(a_[jl][0], b_[rr][0], acc[ja][ra], 0, 0, 0);
            acc[ja][ra] = __builtin_amdgcn_mfma_f32_16x16x32_bf16(a_[jl][1], b_[rr][1], acc[ja][ra], 0, 0, 0);
          }
        __builtin_amdgcn_s_setprio(0);

        if (q != 2) {  // counted wait covering next phase's reads (in-order retire)
          if (lastIt) asm volatile("s_waitcnt vmcnt(0)" ::: "memory");
          else        asm volatile("s_waitcnt vmcnt(8)" ::: "memory");
        }
        __builtin_amdgcn_s_barrier();
      }
    }
  }

  // ---- row-attributed stats from registers ----
  // C/D layout: col = lane&15, row = (lane>>4)*4 + v; frag row = (2j+wm)*16
#pragma unroll
  for (int j = 0; j < 8; j++) {
#pragma unroll
    for (int v = 0; v < 4; v++) {
      int row_l = (2 * j + wm) * 16 + (l >> 4) * 4 + v;
      int grow = row0 + row_l;
      int rl = rowlab[row_l];
      float pmin = 3.0e38f, nmax = -3.0e38f;
#pragma unroll
      for (int r = 0; r < 4; r++) {
        int col_l = (wn + 4 * r) * 16 + (l & 15);
        float s = acc[j][r][v];
        if (rl == collab[col_l]) {
          if ((col0 + col_l) != grow && s < 0.99999f) pmin = fminf(pmin, s);
        } else {
          nmax = fmaxf(nmax, s);
        }
      }
#pragma unroll
      for (int off = 1; off < 16; off <<= 1) {
        pmin = fminf(pmin, __shfl_xor(pmin, off));
        nmax = fmaxf(nmax, __shfl_xor(nmax, off));
      }
      if ((l & 15) == 0) {
        atomicMin(&gpm[grow], fenc(pmin));  // sentinels encode harmless
        atomicMax(&gnm[grow], fenc(nmax));
      }
    }
  }

  // ---- transposed fp16 pack + coalesced store (sim symmetric; 2 row-halves) ----
#pragma unroll
  for (int h = 0; h < 2; h++) {
    __syncthreads();  // previous LDS use done
    unsigned short (*tileT)[TP] = (unsigned short(*)[TP])shraw;
#pragma unroll
    for (int jl = 0; jl < 4; jl++) {
      int j = h * 4 + jl;
      int lr = (2 * jl + wm) * 16 + (l >> 4) * 4;  // local row within half
#pragma unroll
      for (int r = 0; r < 4; r++) {
        int C = (wn + 4 * r) * 16 + (l & 15);
        ushort4v pk;
        pk[0] = f2h(acc[j][r][0]);
        pk[1] = f2h(acc[j][r][1]);
        pk[2] = f2h(acc[j][r][2]);
        pk[3] = f2h(acc[j][r][3]);
        *(ushort4v*)(&tileT[C][lr]) = pk;
      }
    }
    __syncthreads();
    int c = tid >> 1, seg = tid & 1;
    const unsigned short* srcp = &tileT[c][seg * 64];
    unsigned short* dstp = sim + (size_t)(col0 + c) * NB + row0 + h * 128 + seg * 64;
#pragma unroll
    for (int k = 0; k < 8; k++)
      *(short8*)(dstp + k * 8) = *(const short8*)(srcp + k * 8);
  }
}

// ---- kernel 3: streaming masked exp-sums, one wave per row ----
__global__ __launch_bounds__(256) void sums_kernel(const unsigned short* __restrict__ sim,
                                                   const int* __restrict__ labels,
                                                   const unsigned* __restrict__ gpm,
                                                   const unsigned* __restrict__ gnm,
                                                   float* __restrict__ gps,
                                                   float* __restrict__ gns) {
  int t = threadIdx.x, l = t & 63, w = t >> 6;
  int r = blockIdx.x * 4 + w;
  int rl = labels[r];
  float pm = fdec(gpm[r]);  // pos_min (NaN if none -> masks false)
  float nm = fdec(gnm[r]);  // neg_max
  const unsigned short* row = sim + (size_t)r * NB;
  float ps = 0.f, ns = 0.f;
#pragma unroll
  for (int it = 0; it < 8; it++) {
    int j0 = it * 512 + l * 8;
    short8 sv = *(const short8*)(row + j0);
    int4 lb0 = *(const int4*)(labels + j0);
    int4 lb1 = *(const int4*)(labels + j0 + 4);
    int lb[8] = {lb0.x, lb0.y, lb0.z, lb0.w, lb1.x, lb1.y, lb1.z, lb1.w};
#pragma unroll
    for (int e = 0; e < 8; e++) {
      float s = h2f((unsigned short)sv[e]);
      int j = j0 + e;
      if (lb[e] == rl) {
        if (j != r && s < 0.99999f && (s - 0.1f < nm)) ps += __expf(-2.0f * (s - 0.5f));
      } else {
        if (s + 0.1f > pm) ns += __expf(40.0f * (s - 0.5f));
      }
    }
  }
  for (int off = 32; off > 0; off >>= 1) {
    ps += __shfl_down(ps, off);
    ns += __shfl_down(ns, off);
  }
  if (l == 0) { gps[r] = ps; gns[r] = ns; }
}

// ---- kernel 4: finalize scalar loss ----
__global__ __launch_bounds__(256) void finalize_kernel(const float* __restrict__ gps,
                                                       const float* __restrict__ gns,
                                                       float* __restrict__ out) {
  int t = threadIdx.x;
  float sum = 0.f;
  for (int i = t; i < NB; i += 256) {
    float ps = gps[i], ns = gns[i];
    if (ps > 0.f && ns > 0.f) sum += 0.5f * log1pf(ps) + 0.025f * log1pf(ns);
  }
  for (int off = 32; off > 0; off >>= 1) sum += __shfl_down(sum, off);
  __shared__ float wsum[4];
  int lane = t & 63, wid = t >> 6;
  if (lane == 0) wsum[wid] = sum;
  __syncthreads();
  if (t == 0) out[0] = (wsum[0] + wsum[1] + wsum[2] + wsum[3]) / (float)NB;
}

extern "C" void kernel_launch(void* const* d_in, const int* in_sizes, int n_in,
                              void* d_out, int out_size, void* d_ws, size_t ws_size,
                              hipStream_t stream) {
  const float* feats = (const float*)d_in[0];
  const int* labels = (const int*)d_in[1];

  char* ws = (char*)d_ws;
  unsigned short* fb = (unsigned short*)ws;                  // 16 MB bf16 normalized feats
  size_t off = (size_t)NB * ND * 2;
  unsigned short* sim = (unsigned short*)(ws + off);         // 32 MB fp16 sim (full)
  off += (size_t)NB * NB * 2;
  unsigned* gpm = (unsigned*)(ws + off); off += NB * 4;
  unsigned* gnm = (unsigned*)(ws + off); off += NB * 4;
  float* gps = (float*)(ws + off); off += NB * 4;
  float* gns = (float*)(ws + off); off += NB * 4;

  norm_kernel<<<NB, 256, 0, stream>>>(feats, fb, gpm, gnm);
  pass0_kernel<<<NTB * NTB, 512, 0, stream>>>(fb, labels, gpm, gnm, sim);
  sums_kernel<<<NB / 4, 256, 0, stream>>>(sim, labels, gpm, gnm, gps, gns);
  finalize_kernel<<<1, 256, 0, stream>>>(gps, gns, (float*)d_out);
}